// Round 7
// baseline (348.154 us; speedup 1.0000x reference)
//
#include <hip/hip_runtime.h>
#include <math.h>

#define N_NODES 100000
#define N_EDGES 1600000
#define HID 128
#define BN_EPS 1e-5f
#define BM 64
#define IPN 8   // chains walked concurrently per wave

typedef __attribute__((ext_vector_type(8))) short bf16x8;
typedef __attribute__((ext_vector_type(4))) float f32x4;

__device__ inline unsigned short f2bf(float f) {
    unsigned u = __float_as_uint(f);
    unsigned r = u + 0x7FFFu + ((u >> 16) & 1u);   // RNE
    return (unsigned short)(r >> 16);
}
__device__ inline unsigned pk2(float lo, float hi) {
    return (unsigned)f2bf(lo) | ((unsigned)f2bf(hi) << 16);
}
__device__ inline float bflo(unsigned u) { return __uint_as_float(u << 16); }
__device__ inline float bfhi(unsigned u) { return __uint_as_float(u & 0xffff0000u); }

// K1: gate(bf16) = s0*x0 + s1*x1 ; zero shadow ; head = -1
__global__ __launch_bounds__(256) void k_gate(const float* __restrict__ x0,
                                              const float* __restrict__ x1,
                                              const float* __restrict__ mw,
                                              unsigned* __restrict__ gate_u2,  // uint2 view
                                              float* __restrict__ shadow,
                                              int* __restrict__ head) {
    int t = blockIdx.x * 256 + threadIdx.x;            // 4-elem group index, exact grid
    if (blockIdx.x < 64) shadow[t] = 0.0f;
    if (t < N_NODES) head[t] = -1;
    float s0 = 1.0f / (1.0f + expf(-mw[0]));
    float s1 = 1.0f / (1.0f + expf(-mw[1]));
    float4 a = ((const float4*)x0)[t];
    float4 b = ((const float4*)x1)[t];
    uint2 o;
    o.x = pk2(s0 * a.x + s1 * b.x, s0 * a.y + s1 * b.y);
    o.y = pk2(s0 * a.z + s1 * b.z, s0 * a.w + s1 * b.w);
    ((uint2*)gate_u2)[t] = o;
}

// one-time: W1,W2 fp32 [k][n] -> bf16 transposed [n][k]
__global__ __launch_bounds__(256) void k_prep(const float* __restrict__ W1,
                                              const float* __restrict__ W2,
                                              unsigned short* __restrict__ W1T,
                                              unsigned short* __restrict__ W2T) {
    int t = blockIdx.x * 256 + threadIdx.x;            // 16384 threads
    int k = t >> 7, n = t & 127;
    W1T[n * HID + k] = f2bf(W1[t]);
    W2T[n * HID + k] = f2bf(W2[t]);
}

// build per-dst linked list with packed (src, next) nodes; coalesced 8B writes
__global__ __launch_bounds__(256) void k_build(const int* __restrict__ ei,
                                               int* __restrict__ head,
                                               int2* __restrict__ pair) {
    int e = blockIdx.x * 256 + threadIdx.x;            // exact: N_EDGES threads
    int src = ei[e];
    int dst = ei[N_EDGES + e];
    int old = atomicExch(&head[dst], e);
    pair[e] = make_int2(src, old);
}

// gather-sum via 8-way pipelined list walk: one wave per 8 nodes
__global__ __launch_bounds__(256) void k_agg(const unsigned* __restrict__ gu,   // gate bf16 as uint
                                             const int2* __restrict__ pair,
                                             const int* __restrict__ head,
                                             unsigned* __restrict__ hbuf_u) {   // h bf16 as uint
    int wid = threadIdx.x >> 6, lane = threadIdx.x & 63;
    int nbase = (blockIdx.x * 4 + wid) * IPN;          // exact: 3125 blocks
    float sx[IPN], sy[IPN];
    int e[IPN];
    int2 p[IPN];
#pragma unroll
    for (int i = 0; i < IPN; ++i) {
        unsigned g = gu[(nbase + i) * 64 + lane];
        sx[i] = bflo(g); sy[i] = bfhi(g);
        e[i] = head[nbase + i];
    }
    // prologue: first pair load per active chain
#pragma unroll
    for (int i = 0; i < IPN; ++i) if (e[i] >= 0) p[i] = pair[e[i]];
    bool any = false;
#pragma unroll
    for (int i = 0; i < IPN; ++i) any |= (e[i] >= 0);
    while (any) {
        int srcv[IPN], nxv[IPN];
        // stage 1: consume pair, immediately issue NEXT pair load (critical path)
#pragma unroll
        for (int i = 0; i < IPN; ++i) if (e[i] >= 0) {
            srcv[i] = p[i].x;
            nxv[i]  = p[i].y;
            if (nxv[i] >= 0) p[i] = pair[nxv[i]];
        }
        // stage 2: row gathers (off critical path) + accumulate
#pragma unroll
        for (int i = 0; i < IPN; ++i) if (e[i] >= 0) {
            unsigned v = gu[srcv[i] * 64 + lane];
            sx[i] += bflo(v);
            sy[i] += bfhi(v);
            e[i] = nxv[i];
        }
        any = false;
#pragma unroll
        for (int i = 0; i < IPN; ++i) any |= (e[i] >= 0);
    }
#pragma unroll
    for (int i = 0; i < IPN; ++i)
        hbuf_u[(nbase + i) * 64 + lane] = pk2(sx[i], sy[i]);
}

// MFMA MLP: 64-row tile, 4 waves (2x2), wave tile 32x64, K=128 in 4 chunks.
// reads h (bf16), writes h2 (fp32) to h2buf; per-column sums into shadow[64][256].
__global__ __launch_bounds__(256, 2) void k_mlp(const unsigned short* __restrict__ hbuf,
                                                float* __restrict__ h2buf,
                                                const unsigned short* __restrict__ W1T,
                                                const unsigned short* __restrict__ W2T,
                                                const float* __restrict__ b1,
                                                const float* __restrict__ b2,
                                                float* __restrict__ shadow) {
    __shared__ short lds_x[BM * HID];        // 16KB: X, then X2, then colsums
    __shared__ short lds_w1[HID * HID];      // 32KB
    __shared__ short lds_w2[HID * HID];      // 32KB

    const int tid = threadIdx.x;
    const int bid = blockIdx.x;
    const int m0 = bid * BM;

    // stage weights (bf16 W^T [n][k]) with XOR swizzle on 16B chunks
    for (int c = tid; c < 2048; c += 256) {
        int n = c >> 4, k16 = c & 15;
        int4 v1 = ((const int4*)W1T)[c];
        int4 v2 = ((const int4*)W2T)[c];
        int boff = n * 256 + ((k16 * 16) ^ ((n & 7) << 4));
        *(int4*)((char*)lds_w1 + boff) = v1;
        *(int4*)((char*)lds_w2 + boff) = v2;
    }
    // stage X rows (already bf16): straight int4 copy into swizzled layout
    for (int c = tid; c < BM * 16; c += 256) {
        int r = c >> 4, k16 = c & 15;
        int row = m0 + r;
        int4 v = {0, 0, 0, 0};
        if (row < N_NODES)
            v = ((const int4*)(hbuf + (size_t)row * HID))[k16];
        int boff = r * 256 + ((k16 * 16) ^ ((r & 7) << 4));
        *(int4*)((char*)lds_x + boff) = v;
    }

    const int wid = tid >> 6, lane = tid & 63;
    const int wrow = wid >> 1, wcol = wid & 1;
    const int l15 = lane & 15, l4 = lane >> 4;

    float b1g[4], b2g[4];
#pragma unroll
    for (int nf = 0; nf < 4; ++nf) {
        int n = wcol * 64 + nf * 16 + l15;
        b1g[nf] = b1[n];
        b2g[nf] = b2[n];
    }

    __syncthreads();

    // GEMM1: Y = X @ W1
    f32x4 acc1[2][4];
#pragma unroll
    for (int mf = 0; mf < 2; ++mf)
#pragma unroll
        for (int nf = 0; nf < 4; ++nf) acc1[mf][nf] = (f32x4){0.f, 0.f, 0.f, 0.f};

#pragma unroll
    for (int kc = 0; kc < 4; ++kc) {
        bf16x8 av[2], bv[4];
#pragma unroll
        for (int mf = 0; mf < 2; ++mf) {
            int r = wrow * 32 + mf * 16 + l15;
            int boff = r * 256 + (((kc * 64) + l4 * 16) ^ ((r & 7) << 4));
            av[mf] = *(const bf16x8*)((const char*)lds_x + boff);
        }
#pragma unroll
        for (int nf = 0; nf < 4; ++nf) {
            int n = wcol * 64 + nf * 16 + l15;
            int boff = n * 256 + (((kc * 64) + l4 * 16) ^ ((n & 7) << 4));
            bv[nf] = *(const bf16x8*)((const char*)lds_w1 + boff);
        }
#pragma unroll
        for (int mf = 0; mf < 2; ++mf)
#pragma unroll
            for (int nf = 0; nf < 4; ++nf)
                acc1[mf][nf] = __builtin_amdgcn_mfma_f32_16x16x32_bf16(av[mf], bv[nf], acc1[mf][nf], 0, 0, 0);
    }

    __syncthreads();

    // bias1 + ReLU -> X2 (bf16, swizzled) into lds_x
#pragma unroll
    for (int mf = 0; mf < 2; ++mf)
#pragma unroll
        for (int nf = 0; nf < 4; ++nf) {
            int n = wcol * 64 + nf * 16 + l15;
#pragma unroll
            for (int r = 0; r < 4; ++r) {
                int row = wrow * 32 + mf * 16 + l4 * 4 + r;
                float v = fmaxf(acc1[mf][nf][r] + b1g[nf], 0.f);
                int boff = row * 256 + ((2 * n) ^ ((row & 7) << 4));
                *(unsigned short*)((char*)lds_x + boff) = f2bf(v);
            }
        }

    __syncthreads();

    // GEMM2: h2 = X2 @ W2
    f32x4 acc2[2][4];
#pragma unroll
    for (int mf = 0; mf < 2; ++mf)
#pragma unroll
        for (int nf = 0; nf < 4; ++nf) acc2[mf][nf] = (f32x4){0.f, 0.f, 0.f, 0.f};

#pragma unroll
    for (int kc = 0; kc < 4; ++kc) {
        bf16x8 av[2], bv[4];
#pragma unroll
        for (int mf = 0; mf < 2; ++mf) {
            int r = wrow * 32 + mf * 16 + l15;
            int boff = r * 256 + (((kc * 64) + l4 * 16) ^ ((r & 7) << 4));
            av[mf] = *(const bf16x8*)((const char*)lds_x + boff);
        }
#pragma unroll
        for (int nf = 0; nf < 4; ++nf) {
            int n = wcol * 64 + nf * 16 + l15;
            int boff = n * 256 + (((kc * 64) + l4 * 16) ^ ((n & 7) << 4));
            bv[nf] = *(const bf16x8*)((const char*)lds_w2 + boff);
        }
#pragma unroll
        for (int mf = 0; mf < 2; ++mf)
#pragma unroll
            for (int nf = 0; nf < 4; ++nf)
                acc2[mf][nf] = __builtin_amdgcn_mfma_f32_16x16x32_bf16(av[mf], bv[nf], acc2[mf][nf], 0, 0, 0);
    }

    __syncthreads();
    float* cs = (float*)lds_x;
    cs[tid] = 0.f;     // [0..127]=colsum, [128..255]=colsumsq
    __syncthreads();

    // epilogue: bias2, store h2 fp32, column partials
    float psum[4] = {0.f, 0.f, 0.f, 0.f}, psq[4] = {0.f, 0.f, 0.f, 0.f};
#pragma unroll
    for (int mf = 0; mf < 2; ++mf)
#pragma unroll
        for (int nf = 0; nf < 4; ++nf) {
            int n = wcol * 64 + nf * 16 + l15;
#pragma unroll
            for (int r = 0; r < 4; ++r) {
                int row = m0 + wrow * 32 + mf * 16 + l4 * 4 + r;
                float v = acc2[mf][nf][r] + b2g[nf];
                if (row < N_NODES) {
                    h2buf[(size_t)row * HID + n] = v;
                    psum[nf] += v;
                    psq[nf] += v * v;
                }
            }
        }
#pragma unroll
    for (int nf = 0; nf < 4; ++nf) {
        float s = psum[nf], q = psq[nf];
        s += __shfl_xor(s, 16); q += __shfl_xor(q, 16);
        s += __shfl_xor(s, 32); q += __shfl_xor(q, 32);
        if (lane < 16) {
            int n = wcol * 64 + nf * 16 + lane;
            atomicAdd(&cs[n], s);
            atomicAdd(&cs[HID + n], q);
        }
    }
    __syncthreads();
    atomicAdd(&shadow[(bid & 63) * 256 + tid], cs[tid]);
}

// finalize BN scale/shift from shadow partials
__global__ void k_finalize(const float* __restrict__ shadow,
                           const float* __restrict__ gamma,
                           const float* __restrict__ beta,
                           float* __restrict__ sc) {
    int c = threadIdx.x;     // 0..127
    float sum = 0.f, sq = 0.f;
    for (int i = 0; i < 64; ++i) {
        sum += shadow[i * 256 + c];
        sq  += shadow[i * 256 + 128 + c];
    }
    float mean = sum * (1.0f / N_NODES);
    float var  = sq * (1.0f / N_NODES) - mean * mean;
    float r = rsqrtf(var + BN_EPS);
    float scale = gamma[c] * r;
    sc[c]       = scale;
    sc[128 + c] = beta[c] - mean * scale;
}

// in-place BN apply on d_out (reads h2, writes out at same index)
__global__ __launch_bounds__(256) void k_bn(float* __restrict__ buf,
                                            const float* __restrict__ sc) {
    int t = blockIdx.x * 256 + threadIdx.x;
    int c4 = t & 31;
    float4 scale = ((const float4*)sc)[c4];
    float4 shift = ((const float4*)sc)[32 + c4];
    float4 h = ((const float4*)buf)[t];
    float4 o;
    o.x = h.x * scale.x + shift.x;
    o.y = h.y * scale.y + shift.y;
    o.z = h.z * scale.z + shift.z;
    o.w = h.w * scale.w + shift.w;
    ((float4*)buf)[t] = o;
}

extern "C" void kernel_launch(void* const* d_in, const int* in_sizes, int n_in,
                              void* d_out, int out_size, void* d_ws, size_t ws_size,
                              hipStream_t stream) {
    const float* x0 = (const float*)d_in[0];
    const float* x1 = (const float*)d_in[1];
    const int*   ei = (const int*)d_in[2];
    const float* mw = (const float*)d_in[3];
    const float* W1 = (const float*)d_in[4];
    const float* b1 = (const float*)d_in[5];
    const float* W2 = (const float*)d_in[6];
    const float* b2 = (const float*)d_in[7];
    const float* gamma = (const float*)d_in[8];
    const float* beta  = (const float*)d_in[9];

    float* out = (float*)d_out;                            // gate(bf16) -> h2(fp32) -> out

    unsigned short* hbuf = (unsigned short*)d_ws;          // 12.8M bf16 (h)
    float* shadow = (float*)(hbuf + (size_t)N_NODES * HID);// 16384
    float* sc     = shadow + 16384;                        // 256
    unsigned short* W1T = (unsigned short*)(sc + 256);     // 16384 u16
    unsigned short* W2T = W1T + 16384;                     // 16384 u16
    int* head    = (int*)(W2T + 16384);                    // 100,000
    int2* pair   = (int2*)(head + N_NODES + 2);            // 1,600,000 int2 (8B aligned)

    int nthread4 = N_NODES * HID / 4;                      // 3,200,000

    k_gate<<<nthread4 / 256, 256, 0, stream>>>(x0, x1, mw, (unsigned*)out, shadow, head);
    k_prep<<<64, 256, 0, stream>>>(W1, W2, W1T, W2T);
    k_build<<<N_EDGES / 256, 256, 0, stream>>>(ei, head, pair);
    k_agg<<<N_NODES / (4 * IPN), 256, 0, stream>>>((const unsigned*)out, pair, head, (unsigned*)hbuf);
    k_mlp<<<(N_NODES + BM - 1) / BM, 256, 0, stream>>>(hbuf, out, W1T, W2T, b1, b2, shadow);
    k_finalize<<<1, 128, 0, stream>>>(shadow, gamma, beta, sc);
    k_bn<<<nthread4 / 256, 256, 0, stream>>>(out, sc);
}

// Round 8
// 300.891 us; speedup vs baseline: 1.1571x; 1.1571x over previous
//
#include <hip/hip_runtime.h>
#include <math.h>

#define N_NODES 100000
#define N_EDGES 1600000
#define HID 128
#define BN_EPS 1e-5f
#define BM 64
#define NSUB 4   // sublists per node (chain splitting)
#define NPW 2    // nodes per wave (NPW*NSUB = 8 concurrent chains)

typedef __attribute__((ext_vector_type(8))) short bf16x8;
typedef __attribute__((ext_vector_type(4))) float f32x4;

__device__ inline unsigned short f2bf(float f) {
    unsigned u = __float_as_uint(f);
    unsigned r = u + 0x7FFFu + ((u >> 16) & 1u);   // RNE
    return (unsigned short)(r >> 16);
}
__device__ inline unsigned pk2(float lo, float hi) {
    return (unsigned)f2bf(lo) | ((unsigned)f2bf(hi) << 16);
}
__device__ inline float bflo(unsigned u) { return __uint_as_float(u << 16); }
__device__ inline float bfhi(unsigned u) { return __uint_as_float(u & 0xffff0000u); }

// K1: gate(bf16) = s0*x0 + s1*x1 ; zero shadow ; head[4N] = -1
__global__ __launch_bounds__(256) void k_gate(const float* __restrict__ x0,
                                              const float* __restrict__ x1,
                                              const float* __restrict__ mw,
                                              unsigned* __restrict__ gate_u2,  // uint2 view
                                              float* __restrict__ shadow,
                                              int* __restrict__ head) {
    int t = blockIdx.x * 256 + threadIdx.x;            // 4-elem group index, exact grid
    if (blockIdx.x < 64) shadow[t] = 0.0f;
    if (t < NSUB * N_NODES) head[t] = -1;
    float s0 = 1.0f / (1.0f + expf(-mw[0]));
    float s1 = 1.0f / (1.0f + expf(-mw[1]));
    float4 a = ((const float4*)x0)[t];
    float4 b = ((const float4*)x1)[t];
    uint2 o;
    o.x = pk2(s0 * a.x + s1 * b.x, s0 * a.y + s1 * b.y);
    o.y = pk2(s0 * a.z + s1 * b.z, s0 * a.w + s1 * b.w);
    ((uint2*)gate_u2)[t] = o;
}

// one-time: W1,W2 fp32 [k][n] -> bf16 transposed [n][k]
__global__ __launch_bounds__(256) void k_prep(const float* __restrict__ W1,
                                              const float* __restrict__ W2,
                                              unsigned short* __restrict__ W1T,
                                              unsigned short* __restrict__ W2T) {
    int t = blockIdx.x * 256 + threadIdx.x;            // 16384 threads
    int k = t >> 7, n = t & 127;
    W1T[n * HID + k] = f2bf(W1[t]);
    W2T[n * HID + k] = f2bf(W2[t]);
}

// build 4 per-dst linked lists with packed (src, next); coalesced 8B pair writes
__global__ __launch_bounds__(256) void k_build(const int* __restrict__ ei,
                                               int* __restrict__ head,
                                               int2* __restrict__ pair) {
    int e = blockIdx.x * 256 + threadIdx.x;            // exact: N_EDGES threads
    int src = ei[e];
    int dst = ei[N_EDGES + e];
    int old = atomicExch(&head[(e & (NSUB - 1)) * N_NODES + dst], e);
    pair[e] = make_int2(src, old);
}

// gather-sum via 8 short concurrent chains per wave (2 nodes x 4 sublists)
__global__ __launch_bounds__(256) void k_agg(const unsigned* __restrict__ gu,   // gate bf16 as uint
                                             const int2* __restrict__ pair,
                                             const int* __restrict__ head,
                                             unsigned* __restrict__ hbuf_u) {   // h bf16 as uint
    int wid = threadIdx.x >> 6, lane = threadIdx.x & 63;
    int nbase = (blockIdx.x * 4 + wid) * NPW;          // exact: 12500 blocks
    float sx[8], sy[8];
    int e[8];
#pragma unroll
    for (int i = 0; i < 8; ++i) {
        int node = nbase + (i >> 2);
        int sub  = i & 3;
        sx[i] = 0.f; sy[i] = 0.f;
        e[i] = __builtin_amdgcn_readfirstlane(head[sub * N_NODES + node]);
    }
    // self rows into chain j*4
#pragma unroll
    for (int j = 0; j < NPW; ++j) {
        unsigned g = gu[(nbase + j) * 64 + lane];
        sx[j * 4] = bflo(g); sy[j * 4] = bfhi(g);
    }
    bool any = false;
#pragma unroll
    for (int i = 0; i < 8; ++i) any |= (e[i] >= 0);
    while (any) {
        int2 p[8];
        // issue phase: up to 8 independent pair loads (wave-uniform addresses)
#pragma unroll
        for (int i = 0; i < 8; ++i) if (e[i] >= 0) p[i] = pair[e[i]];
        // consume phase: up to 8 independent row gathers, then advance
#pragma unroll
        for (int i = 0; i < 8; ++i) if (e[i] >= 0) {
            unsigned v = gu[p[i].x * 64 + lane];
            sx[i] += bflo(v);
            sy[i] += bfhi(v);
            e[i] = p[i].y;
        }
        any = false;
#pragma unroll
        for (int i = 0; i < 8; ++i) any |= (e[i] >= 0);
    }
#pragma unroll
    for (int j = 0; j < NPW; ++j) {
        float fx = (sx[j*4] + sx[j*4+1]) + (sx[j*4+2] + sx[j*4+3]);
        float fy = (sy[j*4] + sy[j*4+1]) + (sy[j*4+2] + sy[j*4+3]);
        hbuf_u[(nbase + j) * 64 + lane] = pk2(fx, fy);
    }
}

// MFMA MLP: 64-row tile, 4 waves (2x2), wave tile 32x64, K=128 in 4 chunks.
// reads h (bf16), writes h2 (fp32) to h2buf; per-column sums into shadow[64][256].
__global__ __launch_bounds__(256, 2) void k_mlp(const unsigned short* __restrict__ hbuf,
                                                float* __restrict__ h2buf,
                                                const unsigned short* __restrict__ W1T,
                                                const unsigned short* __restrict__ W2T,
                                                const float* __restrict__ b1,
                                                const float* __restrict__ b2,
                                                float* __restrict__ shadow) {
    __shared__ short lds_x[BM * HID];        // 16KB: X, then X2, then colsums
    __shared__ short lds_w1[HID * HID];      // 32KB
    __shared__ short lds_w2[HID * HID];      // 32KB

    const int tid = threadIdx.x;
    const int bid = blockIdx.x;
    const int m0 = bid * BM;

    // stage weights (bf16 W^T [n][k]) with XOR swizzle on 16B chunks
    for (int c = tid; c < 2048; c += 256) {
        int n = c >> 4, k16 = c & 15;
        int4 v1 = ((const int4*)W1T)[c];
        int4 v2 = ((const int4*)W2T)[c];
        int boff = n * 256 + ((k16 * 16) ^ ((n & 7) << 4));
        *(int4*)((char*)lds_w1 + boff) = v1;
        *(int4*)((char*)lds_w2 + boff) = v2;
    }
    // stage X rows (already bf16): straight int4 copy into swizzled layout
    for (int c = tid; c < BM * 16; c += 256) {
        int r = c >> 4, k16 = c & 15;
        int row = m0 + r;
        int4 v = {0, 0, 0, 0};
        if (row < N_NODES)
            v = ((const int4*)(hbuf + (size_t)row * HID))[k16];
        int boff = r * 256 + ((k16 * 16) ^ ((r & 7) << 4));
        *(int4*)((char*)lds_x + boff) = v;
    }

    const int wid = tid >> 6, lane = tid & 63;
    const int wrow = wid >> 1, wcol = wid & 1;
    const int l15 = lane & 15, l4 = lane >> 4;

    float b1g[4], b2g[4];
#pragma unroll
    for (int nf = 0; nf < 4; ++nf) {
        int n = wcol * 64 + nf * 16 + l15;
        b1g[nf] = b1[n];
        b2g[nf] = b2[n];
    }

    __syncthreads();

    // GEMM1: Y = X @ W1
    f32x4 acc1[2][4];
#pragma unroll
    for (int mf = 0; mf < 2; ++mf)
#pragma unroll
        for (int nf = 0; nf < 4; ++nf) acc1[mf][nf] = (f32x4){0.f, 0.f, 0.f, 0.f};

#pragma unroll
    for (int kc = 0; kc < 4; ++kc) {
        bf16x8 av[2], bv[4];
#pragma unroll
        for (int mf = 0; mf < 2; ++mf) {
            int r = wrow * 32 + mf * 16 + l15;
            int boff = r * 256 + (((kc * 64) + l4 * 16) ^ ((r & 7) << 4));
            av[mf] = *(const bf16x8*)((const char*)lds_x + boff);
        }
#pragma unroll
        for (int nf = 0; nf < 4; ++nf) {
            int n = wcol * 64 + nf * 16 + l15;
            int boff = n * 256 + (((kc * 64) + l4 * 16) ^ ((n & 7) << 4));
            bv[nf] = *(const bf16x8*)((const char*)lds_w1 + boff);
        }
#pragma unroll
        for (int mf = 0; mf < 2; ++mf)
#pragma unroll
            for (int nf = 0; nf < 4; ++nf)
                acc1[mf][nf] = __builtin_amdgcn_mfma_f32_16x16x32_bf16(av[mf], bv[nf], acc1[mf][nf], 0, 0, 0);
    }

    __syncthreads();

    // bias1 + ReLU -> X2 (bf16, swizzled) into lds_x
#pragma unroll
    for (int mf = 0; mf < 2; ++mf)
#pragma unroll
        for (int nf = 0; nf < 4; ++nf) {
            int n = wcol * 64 + nf * 16 + l15;
#pragma unroll
            for (int r = 0; r < 4; ++r) {
                int row = wrow * 32 + mf * 16 + l4 * 4 + r;
                float v = fmaxf(acc1[mf][nf][r] + b1g[nf], 0.f);
                int boff = row * 256 + ((2 * n) ^ ((row & 7) << 4));
                *(unsigned short*)((char*)lds_x + boff) = f2bf(v);
            }
        }

    __syncthreads();

    // GEMM2: h2 = X2 @ W2
    f32x4 acc2[2][4];
#pragma unroll
    for (int mf = 0; mf < 2; ++mf)
#pragma unroll
        for (int nf = 0; nf < 4; ++nf) acc2[mf][nf] = (f32x4){0.f, 0.f, 0.f, 0.f};

#pragma unroll
    for (int kc = 0; kc < 4; ++kc) {
        bf16x8 av[2], bv[4];
#pragma unroll
        for (int mf = 0; mf < 2; ++mf) {
            int r = wrow * 32 + mf * 16 + l15;
            int boff = r * 256 + (((kc * 64) + l4 * 16) ^ ((r & 7) << 4));
            av[mf] = *(const bf16x8*)((const char*)lds_x + boff);
        }
#pragma unroll
        for (int nf = 0; nf < 4; ++nf) {
            int n = wcol * 64 + nf * 16 + l15;
            int boff = n * 256 + (((kc * 64) + l4 * 16) ^ ((n & 7) << 4));
            bv[nf] = *(const bf16x8*)((const char*)lds_w2 + boff);
        }
#pragma unroll
        for (int mf = 0; mf < 2; ++mf)
#pragma unroll
            for (int nf = 0; nf < 4; ++nf)
                acc2[mf][nf] = __builtin_amdgcn_mfma_f32_16x16x32_bf16(av[mf], bv[nf], acc2[mf][nf], 0, 0, 0);
    }

    __syncthreads();
    float* cs = (float*)lds_x;
    cs[tid] = 0.f;     // [0..127]=colsum, [128..255]=colsumsq
    __syncthreads();

    // epilogue: bias2, store h2 fp32, column partials
    float psum[4] = {0.f, 0.f, 0.f, 0.f}, psq[4] = {0.f, 0.f, 0.f, 0.f};
#pragma unroll
    for (int mf = 0; mf < 2; ++mf)
#pragma unroll
        for (int nf = 0; nf < 4; ++nf) {
            int n = wcol * 64 + nf * 16 + l15;
#pragma unroll
            for (int r = 0; r < 4; ++r) {
                int row = m0 + wrow * 32 + mf * 16 + l4 * 4 + r;
                float v = acc2[mf][nf][r] + b2g[nf];
                if (row < N_NODES) {
                    h2buf[(size_t)row * HID + n] = v;
                    psum[nf] += v;
                    psq[nf] += v * v;
                }
            }
        }
#pragma unroll
    for (int nf = 0; nf < 4; ++nf) {
        float s = psum[nf], q = psq[nf];
        s += __shfl_xor(s, 16); q += __shfl_xor(q, 16);
        s += __shfl_xor(s, 32); q += __shfl_xor(q, 32);
        if (lane < 16) {
            int n = wcol * 64 + nf * 16 + lane;
            atomicAdd(&cs[n], s);
            atomicAdd(&cs[HID + n], q);
        }
    }
    __syncthreads();
    atomicAdd(&shadow[(bid & 63) * 256 + tid], cs[tid]);
}

// finalize BN scale/shift from shadow partials
__global__ void k_finalize(const float* __restrict__ shadow,
                           const float* __restrict__ gamma,
                           const float* __restrict__ beta,
                           float* __restrict__ sc) {
    int c = threadIdx.x;     // 0..127
    float sum = 0.f, sq = 0.f;
    for (int i = 0; i < 64; ++i) {
        sum += shadow[i * 256 + c];
        sq  += shadow[i * 256 + 128 + c];
    }
    float mean = sum * (1.0f / N_NODES);
    float var  = sq * (1.0f / N_NODES) - mean * mean;
    float r = rsqrtf(var + BN_EPS);
    float scale = gamma[c] * r;
    sc[c]       = scale;
    sc[128 + c] = beta[c] - mean * scale;
}

// in-place BN apply on d_out (reads h2, writes out at same index)
__global__ __launch_bounds__(256) void k_bn(float* __restrict__ buf,
                                            const float* __restrict__ sc) {
    int t = blockIdx.x * 256 + threadIdx.x;
    int c4 = t & 31;
    float4 scale = ((const float4*)sc)[c4];
    float4 shift = ((const float4*)sc)[32 + c4];
    float4 h = ((const float4*)buf)[t];
    float4 o;
    o.x = h.x * scale.x + shift.x;
    o.y = h.y * scale.y + shift.y;
    o.z = h.z * scale.z + shift.z;
    o.w = h.w * scale.w + shift.w;
    ((float4*)buf)[t] = o;
}

extern "C" void kernel_launch(void* const* d_in, const int* in_sizes, int n_in,
                              void* d_out, int out_size, void* d_ws, size_t ws_size,
                              hipStream_t stream) {
    const float* x0 = (const float*)d_in[0];
    const float* x1 = (const float*)d_in[1];
    const int*   ei = (const int*)d_in[2];
    const float* mw = (const float*)d_in[3];
    const float* W1 = (const float*)d_in[4];
    const float* b1 = (const float*)d_in[5];
    const float* W2 = (const float*)d_in[6];
    const float* b2 = (const float*)d_in[7];
    const float* gamma = (const float*)d_in[8];
    const float* beta  = (const float*)d_in[9];

    float* out = (float*)d_out;                            // gate(bf16) -> h2(fp32) -> out

    unsigned short* hbuf = (unsigned short*)d_ws;          // 12.8M bf16 (h)
    float* shadow = (float*)(hbuf + (size_t)N_NODES * HID);// 16384
    float* sc     = shadow + 16384;                        // 256
    unsigned short* W1T = (unsigned short*)(sc + 256);     // 16384 u16
    unsigned short* W2T = W1T + 16384;                     // 16384 u16
    int* head    = (int*)(W2T + 16384);                    // 4 * 100,000
    int2* pair   = (int2*)(head + NSUB * N_NODES);         // 1,600,000 int2 (8B aligned)

    int nthread4 = N_NODES * HID / 4;                      // 3,200,000

    k_gate<<<nthread4 / 256, 256, 0, stream>>>(x0, x1, mw, (unsigned*)out, shadow, head);
    k_prep<<<64, 256, 0, stream>>>(W1, W2, W1T, W2T);
    k_build<<<N_EDGES / 256, 256, 0, stream>>>(ei, head, pair);
    k_agg<<<N_NODES / (4 * NPW), 256, 0, stream>>>((const unsigned*)out, pair, head, (unsigned*)hbuf);
    k_mlp<<<(N_NODES + BM - 1) / BM, 256, 0, stream>>>(hbuf, out, W1T, W2T, b1, b2, shadow);
    k_finalize<<<1, 128, 0, stream>>>(shadow, gamma, beta, sc);
    k_bn<<<nthread4 / 256, 256, 0, stream>>>(out, sc);
}

// Round 9
// 264.555 us; speedup vs baseline: 1.3160x; 1.1373x over previous
//
#include <hip/hip_runtime.h>
#include <math.h>

#define N_NODES 100000
#define N_EDGES 1600000
#define HID 128
#define BN_EPS 1e-5f
#define BM 64
#define NSUB 16   // sublists per node -> avg chain length 1
#define NPW 4     // nodes per wave (NPW*NSUB = 64 chains, one per lane)

typedef __attribute__((ext_vector_type(8))) short bf16x8;
typedef __attribute__((ext_vector_type(4))) float f32x4;

__device__ inline unsigned short f2bf(float f) {
    unsigned u = __float_as_uint(f);
    unsigned r = u + 0x7FFFu + ((u >> 16) & 1u);   // RNE
    return (unsigned short)(r >> 16);
}
__device__ inline unsigned pk2(float lo, float hi) {
    return (unsigned)f2bf(lo) | ((unsigned)f2bf(hi) << 16);
}
__device__ inline float bflo(unsigned u) { return __uint_as_float(u << 16); }
__device__ inline float bfhi(unsigned u) { return __uint_as_float(u & 0xffff0000u); }

// K1: gate(bf16) = s0*x0 + s1*x1 ; zero shadow ; head[16N] = -1 ; W prep folded in
__global__ __launch_bounds__(256) void k_gate(const float* __restrict__ x0,
                                              const float* __restrict__ x1,
                                              const float* __restrict__ mw,
                                              unsigned* __restrict__ gate_u2,
                                              float* __restrict__ shadow,
                                              int* __restrict__ head,
                                              const float* __restrict__ W1,
                                              const float* __restrict__ W2,
                                              unsigned short* __restrict__ W1T,
                                              unsigned short* __restrict__ W2T) {
    int t = blockIdx.x * 256 + threadIdx.x;            // 4-elem group index, exact grid
    if (blockIdx.x < 64) shadow[t] = 0.0f;
    if (t < NSUB * N_NODES) head[t] = -1;
    if (t < HID * HID) {                               // one-time weight transpose+cast
        int k = t >> 7, n = t & 127;
        W1T[n * HID + k] = f2bf(W1[t]);
        W2T[n * HID + k] = f2bf(W2[t]);
    }
    float s0 = 1.0f / (1.0f + expf(-mw[0]));
    float s1 = 1.0f / (1.0f + expf(-mw[1]));
    float4 a = ((const float4*)x0)[t];
    float4 b = ((const float4*)x1)[t];
    uint2 o;
    o.x = pk2(s0 * a.x + s1 * b.x, s0 * a.y + s1 * b.y);
    o.y = pk2(s0 * a.z + s1 * b.z, s0 * a.w + s1 * b.w);
    ((uint2*)gate_u2)[t] = o;
}

// build 16 per-dst linked lists with packed (src, next); coalesced 8B pair writes
__global__ __launch_bounds__(256) void k_build(const int* __restrict__ ei,
                                               int* __restrict__ head,
                                               int2* __restrict__ pair) {
    int e = blockIdx.x * 256 + threadIdx.x;            // exact: N_EDGES threads
    int src = ei[e];
    int dst = ei[N_EDGES + e];
    int old = atomicExch(&head[(e & (NSUB - 1)) * N_NODES + dst], e);
    pair[e] = make_int2(src, old);
}

// gather-sum: 64 chains per wave (one per lane), wave-wide dense row gathers
__global__ __launch_bounds__(256) void k_agg(const unsigned* __restrict__ gu,
                                             const int2* __restrict__ pair,
                                             const int* __restrict__ head,
                                             unsigned* __restrict__ hbuf_u) {
    int wid = threadIdx.x >> 6, lane = threadIdx.x & 63;
    int nbase = (blockIdx.x * 4 + wid) * NPW;          // exact: 6250 blocks
    // lane l owns chain (node nbase + (l>>4), sublist l&15)
    int e = head[(lane & 15) * N_NODES + (nbase + (lane >> 4))];

    float sx[NPW], sy[NPW];
#pragma unroll
    for (int j = 0; j < NPW; ++j) {
        unsigned g = gu[(size_t)(nbase + j) * 64 + lane];   // self row
        sx[j] = bflo(g); sy[j] = bfhi(g);
    }

    while (__any(e >= 0)) {
        int2 pv = make_int2(-1, -1);
        if (e >= 0) pv = pair[e];                      // one dense per-lane clause
#pragma unroll
        for (int j = 0; j < 64; ++j) {
            int sv = __builtin_amdgcn_readlane(pv.x, j);   // SGPR; scalar skip
            if (sv >= 0) {
                unsigned v = gu[(size_t)sv * 64 + lane];   // wave-wide 256B gather
                sx[j >> 4] += bflo(v);
                sy[j >> 4] += bfhi(v);
            }
        }
        e = pv.y;
    }
#pragma unroll
    for (int j = 0; j < NPW; ++j)
        hbuf_u[(size_t)(nbase + j) * 64 + lane] = pk2(sx[j], sy[j]);
}

// MFMA MLP: 64-row tile, 4 waves (2x2), wave tile 32x64, K=128 in 4 chunks.
// reads h (bf16), writes h2 (bf16) IN PLACE; per-column sums into shadow[64][256].
__global__ __launch_bounds__(256, 2) void k_mlp(unsigned short* __restrict__ hbuf,
                                                const unsigned short* __restrict__ W1T,
                                                const unsigned short* __restrict__ W2T,
                                                const float* __restrict__ b1,
                                                const float* __restrict__ b2,
                                                float* __restrict__ shadow) {
    __shared__ short lds_x[BM * HID];        // 16KB: X, then X2, then colsums
    __shared__ short lds_w1[HID * HID];      // 32KB
    __shared__ short lds_w2[HID * HID];      // 32KB

    const int tid = threadIdx.x;
    const int bid = blockIdx.x;
    const int m0 = bid * BM;

    // stage weights (bf16 W^T [n][k]) with XOR swizzle on 16B chunks
    for (int c = tid; c < 2048; c += 256) {
        int n = c >> 4, k16 = c & 15;
        int4 v1 = ((const int4*)W1T)[c];
        int4 v2 = ((const int4*)W2T)[c];
        int boff = n * 256 + ((k16 * 16) ^ ((n & 7) << 4));
        *(int4*)((char*)lds_w1 + boff) = v1;
        *(int4*)((char*)lds_w2 + boff) = v2;
    }
    // stage X rows (already bf16): straight int4 copy into swizzled layout
    for (int c = tid; c < BM * 16; c += 256) {
        int r = c >> 4, k16 = c & 15;
        int row = m0 + r;
        int4 v = {0, 0, 0, 0};
        if (row < N_NODES)
            v = ((const int4*)(hbuf + (size_t)row * HID))[k16];
        int boff = r * 256 + ((k16 * 16) ^ ((r & 7) << 4));
        *(int4*)((char*)lds_x + boff) = v;
    }

    const int wid = tid >> 6, lane = tid & 63;
    const int wrow = wid >> 1, wcol = wid & 1;
    const int l15 = lane & 15, l4 = lane >> 4;

    float b1g[4], b2g[4];
#pragma unroll
    for (int nf = 0; nf < 4; ++nf) {
        int n = wcol * 64 + nf * 16 + l15;
        b1g[nf] = b1[n];
        b2g[nf] = b2[n];
    }

    __syncthreads();

    // GEMM1: Y = X @ W1
    f32x4 acc1[2][4];
#pragma unroll
    for (int mf = 0; mf < 2; ++mf)
#pragma unroll
        for (int nf = 0; nf < 4; ++nf) acc1[mf][nf] = (f32x4){0.f, 0.f, 0.f, 0.f};

#pragma unroll
    for (int kc = 0; kc < 4; ++kc) {
        bf16x8 av[2], bv[4];
#pragma unroll
        for (int mf = 0; mf < 2; ++mf) {
            int r = wrow * 32 + mf * 16 + l15;
            int boff = r * 256 + (((kc * 64) + l4 * 16) ^ ((r & 7) << 4));
            av[mf] = *(const bf16x8*)((const char*)lds_x + boff);
        }
#pragma unroll
        for (int nf = 0; nf < 4; ++nf) {
            int n = wcol * 64 + nf * 16 + l15;
            int boff = n * 256 + (((kc * 64) + l4 * 16) ^ ((n & 7) << 4));
            bv[nf] = *(const bf16x8*)((const char*)lds_w1 + boff);
        }
#pragma unroll
        for (int mf = 0; mf < 2; ++mf)
#pragma unroll
            for (int nf = 0; nf < 4; ++nf)
                acc1[mf][nf] = __builtin_amdgcn_mfma_f32_16x16x32_bf16(av[mf], bv[nf], acc1[mf][nf], 0, 0, 0);
    }

    __syncthreads();

    // bias1 + ReLU -> X2 (bf16, swizzled) into lds_x
#pragma unroll
    for (int mf = 0; mf < 2; ++mf)
#pragma unroll
        for (int nf = 0; nf < 4; ++nf) {
            int n = wcol * 64 + nf * 16 + l15;
#pragma unroll
            for (int r = 0; r < 4; ++r) {
                int row = wrow * 32 + mf * 16 + l4 * 4 + r;
                float v = fmaxf(acc1[mf][nf][r] + b1g[nf], 0.f);
                int boff = row * 256 + ((2 * n) ^ ((row & 7) << 4));
                *(unsigned short*)((char*)lds_x + boff) = f2bf(v);
            }
        }

    __syncthreads();

    // GEMM2: h2 = X2 @ W2
    f32x4 acc2[2][4];
#pragma unroll
    for (int mf = 0; mf < 2; ++mf)
#pragma unroll
        for (int nf = 0; nf < 4; ++nf) acc2[mf][nf] = (f32x4){0.f, 0.f, 0.f, 0.f};

#pragma unroll
    for (int kc = 0; kc < 4; ++kc) {
        bf16x8 av[2], bv[4];
#pragma unroll
        for (int mf = 0; mf < 2; ++mf) {
            int r = wrow * 32 + mf * 16 + l15;
            int boff = r * 256 + (((kc * 64) + l4 * 16) ^ ((r & 7) << 4));
            av[mf] = *(const bf16x8*)((const char*)lds_x + boff);
        }
#pragma unroll
        for (int nf = 0; nf < 4; ++nf) {
            int n = wcol * 64 + nf * 16 + l15;
            int boff = n * 256 + (((kc * 64) + l4 * 16) ^ ((n & 7) << 4));
            bv[nf] = *(const bf16x8*)((const char*)lds_w2 + boff);
        }
#pragma unroll
        for (int mf = 0; mf < 2; ++mf)
#pragma unroll
            for (int nf = 0; nf < 4; ++nf)
                acc2[mf][nf] = __builtin_amdgcn_mfma_f32_16x16x32_bf16(av[mf], bv[nf], acc2[mf][nf], 0, 0, 0);
    }

    __syncthreads();
    float* cs = (float*)lds_x;
    cs[tid] = 0.f;     // [0..127]=colsum, [128..255]=colsumsq
    __syncthreads();

    // epilogue: bias2, quantize h2 -> bf16 in place, column partials (of quantized)
    float psum[4] = {0.f, 0.f, 0.f, 0.f}, psq[4] = {0.f, 0.f, 0.f, 0.f};
#pragma unroll
    for (int mf = 0; mf < 2; ++mf)
#pragma unroll
        for (int nf = 0; nf < 4; ++nf) {
            int n = wcol * 64 + nf * 16 + l15;
#pragma unroll
            for (int r = 0; r < 4; ++r) {
                int row = m0 + wrow * 32 + mf * 16 + l4 * 4 + r;
                float v = acc2[mf][nf][r] + b2g[nf];
                if (row < N_NODES) {
                    unsigned short q = f2bf(v);
                    float vq = __uint_as_float(((unsigned)q) << 16);
                    hbuf[(size_t)row * HID + n] = q;
                    psum[nf] += vq;
                    psq[nf] += vq * vq;
                }
            }
        }
#pragma unroll
    for (int nf = 0; nf < 4; ++nf) {
        float s = psum[nf], q = psq[nf];
        s += __shfl_xor(s, 16); q += __shfl_xor(q, 16);
        s += __shfl_xor(s, 32); q += __shfl_xor(q, 32);
        if (lane < 16) {
            int n = wcol * 64 + nf * 16 + lane;
            atomicAdd(&cs[n], s);
            atomicAdd(&cs[HID + n], q);
        }
    }
    __syncthreads();
    atomicAdd(&shadow[(bid & 63) * 256 + tid], cs[tid]);
}

// finalize BN scale/shift from shadow partials
__global__ void k_finalize(const float* __restrict__ shadow,
                           const float* __restrict__ gamma,
                           const float* __restrict__ beta,
                           float* __restrict__ sc) {
    int c = threadIdx.x;     // 0..127
    float sum = 0.f, sq = 0.f;
    for (int i = 0; i < 64; ++i) {
        sum += shadow[i * 256 + c];
        sq  += shadow[i * 256 + 128 + c];
    }
    float mean = sum * (1.0f / N_NODES);
    float var  = sq * (1.0f / N_NODES) - mean * mean;
    float r = rsqrtf(var + BN_EPS);
    float scale = gamma[c] * r;
    sc[c]       = scale;
    sc[128 + c] = beta[c] - mean * scale;
}

// BN apply: read bf16 h2, write fp32 out
__global__ __launch_bounds__(256) void k_bn(const unsigned short* __restrict__ h2,
                                            const float* __restrict__ sc,
                                            float* __restrict__ out) {
    int t = blockIdx.x * 256 + threadIdx.x;            // 4-channel group index
    int c4 = t & 31;
    float4 scale = ((const float4*)sc)[c4];
    float4 shift = ((const float4*)sc)[32 + c4];
    uint2 hv = ((const uint2*)h2)[t];
    float4 o;
    o.x = bflo(hv.x) * scale.x + shift.x;
    o.y = bfhi(hv.x) * scale.y + shift.y;
    o.z = bflo(hv.y) * scale.z + shift.z;
    o.w = bfhi(hv.y) * scale.w + shift.w;
    ((float4*)out)[t] = o;
}

extern "C" void kernel_launch(void* const* d_in, const int* in_sizes, int n_in,
                              void* d_out, int out_size, void* d_ws, size_t ws_size,
                              hipStream_t stream) {
    const float* x0 = (const float*)d_in[0];
    const float* x1 = (const float*)d_in[1];
    const int*   ei = (const int*)d_in[2];
    const float* mw = (const float*)d_in[3];
    const float* W1 = (const float*)d_in[4];
    const float* b1 = (const float*)d_in[5];
    const float* W2 = (const float*)d_in[6];
    const float* b2 = (const float*)d_in[7];
    const float* gamma = (const float*)d_in[8];
    const float* beta  = (const float*)d_in[9];

    float* out = (float*)d_out;                            // gate(bf16) scratch -> final fp32

    unsigned short* hbuf = (unsigned short*)d_ws;          // 12.8M bf16 (h, then h2)
    float* shadow = (float*)(hbuf + (size_t)N_NODES * HID);// 16384
    float* sc     = shadow + 16384;                        // 256
    unsigned short* W1T = (unsigned short*)(sc + 256);     // 16384 u16
    unsigned short* W2T = W1T + 16384;                     // 16384 u16
    int* head    = (int*)(W2T + 16384);                    // 16 * 100,000
    int2* pair   = (int2*)(head + NSUB * N_NODES);         // 1,600,000 int2 (8B aligned)

    int nthread4 = N_NODES * HID / 4;                      // 3,200,000

    k_gate<<<nthread4 / 256, 256, 0, stream>>>(x0, x1, mw, (unsigned*)out, shadow, head,
                                               W1, W2, W1T, W2T);
    k_build<<<N_EDGES / 256, 256, 0, stream>>>(ei, head, pair);
    k_agg<<<N_NODES / (4 * NPW), 256, 0, stream>>>((const unsigned*)out, pair, head,
                                                   (unsigned*)hbuf);
    k_mlp<<<(N_NODES + BM - 1) / BM, 256, 0, stream>>>(hbuf, W1T, W2T, b1, b2, shadow);
    k_finalize<<<1, 128, 0, stream>>>(shadow, gamma, beta, sc);
    k_bn<<<nthread4 / 256, 256, 0, stream>>>(hbuf, sc, out);
}

// Round 10
// 253.075 us; speedup vs baseline: 1.3757x; 1.0454x over previous
//
#include <hip/hip_runtime.h>
#include <math.h>

#define N_NODES 100000
#define N_EDGES 1600000
#define HID 128
#define BN_EPS 1e-5f
#define BM 64
#define NTILES ((N_NODES + BM - 1) / BM)   // 1563
#define MLP_BLOCKS 512
#define NSUB 16   // sublists per node -> avg chain length 1
#define NPW 4     // nodes per wave (NPW*NSUB = 64 chains, one per lane)

typedef __attribute__((ext_vector_type(8))) short bf16x8;
typedef __attribute__((ext_vector_type(4))) float f32x4;

__device__ inline unsigned short f2bf(float f) {
    unsigned u = __float_as_uint(f);
    unsigned r = u + 0x7FFFu + ((u >> 16) & 1u);   // RNE
    return (unsigned short)(r >> 16);
}
__device__ inline unsigned pk2(float lo, float hi) {
    return (unsigned)f2bf(lo) | ((unsigned)f2bf(hi) << 16);
}
__device__ inline float bflo(unsigned u) { return __uint_as_float(u << 16); }
__device__ inline float bfhi(unsigned u) { return __uint_as_float(u & 0xffff0000u); }

// K1: gate(bf16) = s0*x0 + s1*x1 ; zero shadow ; head[16N] = -1 ; W prep folded in
__global__ __launch_bounds__(256) void k_gate(const float* __restrict__ x0,
                                              const float* __restrict__ x1,
                                              const float* __restrict__ mw,
                                              unsigned* __restrict__ gate_u2,
                                              float* __restrict__ shadow,
                                              int* __restrict__ head,
                                              const float* __restrict__ W1,
                                              const float* __restrict__ W2,
                                              unsigned short* __restrict__ W1T,
                                              unsigned short* __restrict__ W2T) {
    int t = blockIdx.x * 256 + threadIdx.x;            // 4-elem group index, exact grid
    if (blockIdx.x < 64) shadow[t] = 0.0f;
    if (t < NSUB * N_NODES) head[t] = -1;
    if (t < HID * HID) {                               // one-time weight transpose+cast
        int k = t >> 7, n = t & 127;
        W1T[n * HID + k] = f2bf(W1[t]);
        W2T[n * HID + k] = f2bf(W2[t]);
    }
    float s0 = 1.0f / (1.0f + expf(-mw[0]));
    float s1 = 1.0f / (1.0f + expf(-mw[1]));
    float4 a = ((const float4*)x0)[t];
    float4 b = ((const float4*)x1)[t];
    uint2 o;
    o.x = pk2(s0 * a.x + s1 * b.x, s0 * a.y + s1 * b.y);
    o.y = pk2(s0 * a.z + s1 * b.z, s0 * a.w + s1 * b.w);
    ((uint2*)gate_u2)[t] = o;
}

// build 16 per-dst linked lists with packed (src, next); coalesced 8B pair writes
__global__ __launch_bounds__(256) void k_build(const int* __restrict__ ei,
                                               int* __restrict__ head,
                                               int2* __restrict__ pair) {
    int e = blockIdx.x * 256 + threadIdx.x;            // exact: N_EDGES threads
    int src = ei[e];
    int dst = ei[N_EDGES + e];
    int old = atomicExch(&head[(e & (NSUB - 1)) * N_NODES + dst], e);
    pair[e] = make_int2(src, old);
}

// gather-sum: 64 chains per wave (one per lane), wave-wide dense row gathers
__global__ __launch_bounds__(256) void k_agg(const unsigned* __restrict__ gu,
                                             const int2* __restrict__ pair,
                                             const int* __restrict__ head,
                                             unsigned* __restrict__ hbuf_u) {
    int wid = threadIdx.x >> 6, lane = threadIdx.x & 63;
    int nbase = (blockIdx.x * 4 + wid) * NPW;          // exact: 6250 blocks
    // lane l owns chain (node nbase + (l>>4), sublist l&15)
    int e = head[(lane & 15) * N_NODES + (nbase + (lane >> 4))];

    float sx[NPW], sy[NPW];
#pragma unroll
    for (int j = 0; j < NPW; ++j) {
        unsigned g = gu[(size_t)(nbase + j) * 64 + lane];   // self row
        sx[j] = bflo(g); sy[j] = bfhi(g);
    }

    while (__any(e >= 0)) {
        int2 pv = make_int2(-1, -1);
        if (e >= 0) pv = pair[e];                      // one dense per-lane clause
#pragma unroll
        for (int j = 0; j < 64; ++j) {
            int sv = __builtin_amdgcn_readlane(pv.x, j);   // SGPR; scalar skip
            if (sv >= 0) {
                unsigned v = gu[(size_t)sv * 64 + lane];   // wave-wide 256B gather
                sx[j >> 4] += bflo(v);
                sy[j >> 4] += bfhi(v);
            }
        }
        e = pv.y;
    }
#pragma unroll
    for (int j = 0; j < NPW; ++j)
        hbuf_u[(size_t)(nbase + j) * 64 + lane] = pk2(sx[j], sy[j]);
}

// Persistent MFMA MLP: 512 blocks, weights staged ONCE per block, loop over tiles.
// reads h (bf16), writes h2 (bf16) IN PLACE; column sums in regs -> shadow at end.
__global__ __launch_bounds__(256, 2) void k_mlp(unsigned short* __restrict__ hbuf,
                                                const unsigned short* __restrict__ W1T,
                                                const unsigned short* __restrict__ W2T,
                                                const float* __restrict__ b1,
                                                const float* __restrict__ b2,
                                                float* __restrict__ shadow) {
    __shared__ short lds_x[BM * HID];        // 16KB: X / X2 per tile, colsums at end
    __shared__ short lds_w1[HID * HID];      // 32KB
    __shared__ short lds_w2[HID * HID];      // 32KB

    const int tid = threadIdx.x;

    // stage weights once (bf16 W^T [n][k]) with XOR swizzle on 16B chunks
    for (int c = tid; c < 2048; c += 256) {
        int n = c >> 4, k16 = c & 15;
        int4 v1 = ((const int4*)W1T)[c];
        int4 v2 = ((const int4*)W2T)[c];
        int boff = n * 256 + ((k16 * 16) ^ ((n & 7) << 4));
        *(int4*)((char*)lds_w1 + boff) = v1;
        *(int4*)((char*)lds_w2 + boff) = v2;
    }

    const int wid = tid >> 6, lane = tid & 63;
    const int wrow = wid >> 1, wcol = wid & 1;
    const int l15 = lane & 15, l4 = lane >> 4;

    float b1g[4], b2g[4];
#pragma unroll
    for (int nf = 0; nf < 4; ++nf) {
        int n = wcol * 64 + nf * 16 + l15;
        b1g[nf] = b1[n];
        b2g[nf] = b2[n];
    }

    float psum[4] = {0.f, 0.f, 0.f, 0.f}, psq[4] = {0.f, 0.f, 0.f, 0.f};

    __syncthreads();   // weights ready

    for (int tile = blockIdx.x; tile < NTILES; tile += MLP_BLOCKS) {
        const int m0 = tile * BM;

        // stage X rows (already bf16): int4 copy into swizzled layout
        for (int c = tid; c < BM * 16; c += 256) {
            int r = c >> 4, k16 = c & 15;
            int row = m0 + r;
            int4 v = {0, 0, 0, 0};
            if (row < N_NODES)
                v = ((const int4*)(hbuf + (size_t)row * HID))[k16];
            int boff = r * 256 + ((k16 * 16) ^ ((r & 7) << 4));
            *(int4*)((char*)lds_x + boff) = v;
        }
        __syncthreads();

        // GEMM1: Y = X @ W1
        f32x4 acc1[2][4];
#pragma unroll
        for (int mf = 0; mf < 2; ++mf)
#pragma unroll
            for (int nf = 0; nf < 4; ++nf) acc1[mf][nf] = (f32x4){0.f, 0.f, 0.f, 0.f};

#pragma unroll
        for (int kc = 0; kc < 4; ++kc) {
            bf16x8 av[2], bv[4];
#pragma unroll
            for (int mf = 0; mf < 2; ++mf) {
                int r = wrow * 32 + mf * 16 + l15;
                int boff = r * 256 + (((kc * 64) + l4 * 16) ^ ((r & 7) << 4));
                av[mf] = *(const bf16x8*)((const char*)lds_x + boff);
            }
#pragma unroll
            for (int nf = 0; nf < 4; ++nf) {
                int n = wcol * 64 + nf * 16 + l15;
                int boff = n * 256 + (((kc * 64) + l4 * 16) ^ ((n & 7) << 4));
                bv[nf] = *(const bf16x8*)((const char*)lds_w1 + boff);
            }
#pragma unroll
            for (int mf = 0; mf < 2; ++mf)
#pragma unroll
                for (int nf = 0; nf < 4; ++nf)
                    acc1[mf][nf] = __builtin_amdgcn_mfma_f32_16x16x32_bf16(av[mf], bv[nf], acc1[mf][nf], 0, 0, 0);
        }

        __syncthreads();

        // bias1 + ReLU -> X2 (bf16, swizzled) into lds_x
#pragma unroll
        for (int mf = 0; mf < 2; ++mf)
#pragma unroll
            for (int nf = 0; nf < 4; ++nf) {
                int n = wcol * 64 + nf * 16 + l15;
#pragma unroll
                for (int r = 0; r < 4; ++r) {
                    int row = wrow * 32 + mf * 16 + l4 * 4 + r;
                    float v = fmaxf(acc1[mf][nf][r] + b1g[nf], 0.f);
                    int boff = row * 256 + ((2 * n) ^ ((row & 7) << 4));
                    *(unsigned short*)((char*)lds_x + boff) = f2bf(v);
                }
            }

        __syncthreads();

        // GEMM2: h2 = X2 @ W2
        f32x4 acc2[2][4];
#pragma unroll
        for (int mf = 0; mf < 2; ++mf)
#pragma unroll
            for (int nf = 0; nf < 4; ++nf) acc2[mf][nf] = (f32x4){0.f, 0.f, 0.f, 0.f};

#pragma unroll
        for (int kc = 0; kc < 4; ++kc) {
            bf16x8 av[2], bv[4];
#pragma unroll
            for (int mf = 0; mf < 2; ++mf) {
                int r = wrow * 32 + mf * 16 + l15;
                int boff = r * 256 + (((kc * 64) + l4 * 16) ^ ((r & 7) << 4));
                av[mf] = *(const bf16x8*)((const char*)lds_x + boff);
            }
#pragma unroll
            for (int nf = 0; nf < 4; ++nf) {
                int n = wcol * 64 + nf * 16 + l15;
                int boff = n * 256 + (((kc * 64) + l4 * 16) ^ ((n & 7) << 4));
                bv[nf] = *(const bf16x8*)((const char*)lds_w2 + boff);
            }
#pragma unroll
            for (int mf = 0; mf < 2; ++mf)
#pragma unroll
                for (int nf = 0; nf < 4; ++nf)
                    acc2[mf][nf] = __builtin_amdgcn_mfma_f32_16x16x32_bf16(av[mf], bv[nf], acc2[mf][nf], 0, 0, 0);
        }

        // epilogue: bias2, quantize h2 -> bf16 in place, column partials in regs
#pragma unroll
        for (int mf = 0; mf < 2; ++mf)
#pragma unroll
            for (int nf = 0; nf < 4; ++nf) {
                int n = wcol * 64 + nf * 16 + l15;
#pragma unroll
                for (int r = 0; r < 4; ++r) {
                    int row = m0 + wrow * 32 + mf * 16 + l4 * 4 + r;
                    float v = acc2[mf][nf][r] + b2g[nf];
                    if (row < N_NODES) {
                        unsigned short q = f2bf(v);
                        float vq = __uint_as_float(((unsigned)q) << 16);
                        hbuf[(size_t)row * HID + n] = q;
                        psum[nf] += vq;
                        psq[nf] += vq * vq;
                    }
                }
            }

        __syncthreads();   // all GEMM2 LDS reads done before next tile's X staging
    }

    // final column-sum reduction: wave shuffle -> LDS -> one shadow add
    float* cs = (float*)lds_x;
    cs[tid] = 0.f;
    __syncthreads();
#pragma unroll
    for (int nf = 0; nf < 4; ++nf) {
        float s = psum[nf], q = psq[nf];
        s += __shfl_xor(s, 16); q += __shfl_xor(q, 16);
        s += __shfl_xor(s, 32); q += __shfl_xor(q, 32);
        if (lane < 16) {
            int n = wcol * 64 + nf * 16 + lane;
            atomicAdd(&cs[n], s);
            atomicAdd(&cs[HID + n], q);
        }
    }
    __syncthreads();
    atomicAdd(&shadow[(blockIdx.x & 63) * 256 + tid], cs[tid]);
}

// finalize BN scale/shift from shadow partials
__global__ void k_finalize(const float* __restrict__ shadow,
                           const float* __restrict__ gamma,
                           const float* __restrict__ beta,
                           float* __restrict__ sc) {
    int c = threadIdx.x;     // 0..127
    float sum = 0.f, sq = 0.f;
    for (int i = 0; i < 64; ++i) {
        sum += shadow[i * 256 + c];
        sq  += shadow[i * 256 + 128 + c];
    }
    float mean = sum * (1.0f / N_NODES);
    float var  = sq * (1.0f / N_NODES) - mean * mean;
    float r = rsqrtf(var + BN_EPS);
    float scale = gamma[c] * r;
    sc[c]       = scale;
    sc[128 + c] = beta[c] - mean * scale;
}

// BN apply: read bf16 h2, write fp32 out
__global__ __launch_bounds__(256) void k_bn(const unsigned short* __restrict__ h2,
                                            const float* __restrict__ sc,
                                            float* __restrict__ out) {
    int t = blockIdx.x * 256 + threadIdx.x;            // 4-channel group index
    int c4 = t & 31;
    float4 scale = ((const float4*)sc)[c4];
    float4 shift = ((const float4*)sc)[32 + c4];
    uint2 hv = ((const uint2*)h2)[t];
    float4 o;
    o.x = bflo(hv.x) * scale.x + shift.x;
    o.y = bfhi(hv.x) * scale.y + shift.y;
    o.z = bflo(hv.y) * scale.z + shift.z;
    o.w = bfhi(hv.y) * scale.w + shift.w;
    ((float4*)out)[t] = o;
}

extern "C" void kernel_launch(void* const* d_in, const int* in_sizes, int n_in,
                              void* d_out, int out_size, void* d_ws, size_t ws_size,
                              hipStream_t stream) {
    const float* x0 = (const float*)d_in[0];
    const float* x1 = (const float*)d_in[1];
    const int*   ei = (const int*)d_in[2];
    const float* mw = (const float*)d_in[3];
    const float* W1 = (const float*)d_in[4];
    const float* b1 = (const float*)d_in[5];
    const float* W2 = (const float*)d_in[6];
    const float* b2 = (const float*)d_in[7];
    const float* gamma = (const float*)d_in[8];
    const float* beta  = (const float*)d_in[9];

    float* out = (float*)d_out;                            // gate(bf16) scratch -> final fp32

    unsigned short* hbuf = (unsigned short*)d_ws;          // 12.8M bf16 (h, then h2)
    float* shadow = (float*)(hbuf + (size_t)N_NODES * HID);// 16384
    float* sc     = shadow + 16384;                        // 256
    unsigned short* W1T = (unsigned short*)(sc + 256);     // 16384 u16
    unsigned short* W2T = W1T + 16384;                     // 16384 u16
    int* head    = (int*)(W2T + 16384);                    // 16 * 100,000
    int2* pair   = (int2*)(head + NSUB * N_NODES);         // 1,600,000 int2 (8B aligned)

    int nthread4 = N_NODES * HID / 4;                      // 3,200,000

    k_gate<<<nthread4 / 256, 256, 0, stream>>>(x0, x1, mw, (unsigned*)out, shadow, head,
                                               W1, W2, W1T, W2T);
    k_build<<<N_EDGES / 256, 256, 0, stream>>>(ei, head, pair);
    k_agg<<<N_NODES / (4 * NPW), 256, 0, stream>>>((const unsigned*)out, pair, head,
                                                   (unsigned*)hbuf);
    k_mlp<<<MLP_BLOCKS, 256, 0, stream>>>(hbuf, W1T, W2T, b1, b2, shadow);
    k_finalize<<<1, 128, 0, stream>>>(shadow, gamma, beta, sc);
    k_bn<<<nthread4 / 256, 256, 0, stream>>>(hbuf, sc, out);
}

// Round 11
// 242.111 us; speedup vs baseline: 1.4380x; 1.0453x over previous
//
#include <hip/hip_runtime.h>
#include <math.h>

#define N_NODES 100000
#define N_EDGES 1600000
#define HID 128
#define BN_EPS 1e-5f
#define BM 64
#define NTILES ((N_NODES + BM - 1) / BM)   // 1563
#define MLP_BLOCKS 512
#define NSUB 16   // sublists per node -> avg chain length 1
#define NPW 4     // nodes per wave (NPW*NSUB = 64 chains, one per lane)
#define BN_BLOCKS 512

typedef __attribute__((ext_vector_type(8))) short bf16x8;
typedef __attribute__((ext_vector_type(4))) float f32x4;

__device__ inline unsigned short f2bf(float f) {
    unsigned u = __float_as_uint(f);
    unsigned r = u + 0x7FFFu + ((u >> 16) & 1u);   // RNE
    return (unsigned short)(r >> 16);
}
__device__ inline unsigned pk2(float lo, float hi) {
    return (unsigned)f2bf(lo) | ((unsigned)f2bf(hi) << 16);
}
__device__ inline float bflo(unsigned u) { return __uint_as_float(u << 16); }
__device__ inline float bfhi(unsigned u) { return __uint_as_float(u & 0xffff0000u); }

// Fused front: 2/3 of blocks do gate (bf16 cast + shadow zero + W prep),
// 1/3 do linked-list build. Independent work; head pre-initialized by memset.
__global__ __launch_bounds__(256) void k_front(const float* __restrict__ x0,
                                               const float* __restrict__ x1,
                                               const float* __restrict__ mw,
                                               unsigned* __restrict__ gate_u2,
                                               float* __restrict__ shadow,
                                               const float* __restrict__ W1,
                                               const float* __restrict__ W2,
                                               unsigned short* __restrict__ W1T,
                                               unsigned short* __restrict__ W2T,
                                               const int* __restrict__ ei,
                                               int* __restrict__ head,
                                               int2* __restrict__ pair) {
    int bid = blockIdx.x, tid = threadIdx.x;
    int role = bid % 3;
    if (role < 2) {
        // gate block: gid in [0, 12500)
        int gid = (bid / 3) * 2 + role;
        int t = gid * 256 + tid;                       // 4-elem group index
        if (gid < 64) {
            shadow[t] = 0.0f;
            int k = t >> 7, n = t & 127;               // t < 16384
            W1T[n * HID + k] = f2bf(W1[t]);
            W2T[n * HID + k] = f2bf(W2[t]);
        }
        float s0 = 1.0f / (1.0f + expf(-mw[0]));
        float s1 = 1.0f / (1.0f + expf(-mw[1]));
        float4 a = ((const float4*)x0)[t];
        float4 b = ((const float4*)x1)[t];
        uint2 o;
        o.x = pk2(s0 * a.x + s1 * b.x, s0 * a.y + s1 * b.y);
        o.y = pk2(s0 * a.z + s1 * b.z, s0 * a.w + s1 * b.w);
        ((uint2*)gate_u2)[t] = o;
    } else {
        // build block: gid in [0, 6250)
        int e = (bid / 3) * 256 + tid;                 // exact: N_EDGES threads
        int src = ei[e];
        int dst = ei[N_EDGES + e];
        int old = atomicExch(&head[(e & (NSUB - 1)) * N_NODES + dst], e);
        pair[e] = make_int2(src, old);
    }
}

// gather-sum: 64 chains per wave (one per lane), wave-wide dense row gathers
__global__ __launch_bounds__(256) void k_agg(const unsigned* __restrict__ gu,
                                             const int2* __restrict__ pair,
                                             const int* __restrict__ head,
                                             unsigned* __restrict__ hbuf_u) {
    int wid = threadIdx.x >> 6, lane = threadIdx.x & 63;
    int nbase = (blockIdx.x * 4 + wid) * NPW;          // exact: 6250 blocks
    // lane l owns chain (node nbase + (l>>4), sublist l&15)
    int e = head[(lane & 15) * N_NODES + (nbase + (lane >> 4))];

    float sx[NPW], sy[NPW];
#pragma unroll
    for (int j = 0; j < NPW; ++j) {
        unsigned g = gu[(size_t)(nbase + j) * 64 + lane];   // self row
        sx[j] = bflo(g); sy[j] = bfhi(g);
    }

    while (__any(e >= 0)) {
        int2 pv = make_int2(-1, -1);
        if (e >= 0) pv = pair[e];                      // one dense per-lane clause
#pragma unroll
        for (int j = 0; j < 64; ++j) {
            int sv = __builtin_amdgcn_readlane(pv.x, j);   // SGPR; scalar skip
            if (sv >= 0) {
                unsigned v = gu[(size_t)sv * 64 + lane];   // wave-wide 256B gather
                sx[j >> 4] += bflo(v);
                sy[j >> 4] += bfhi(v);
            }
        }
        e = pv.y;
    }
#pragma unroll
    for (int j = 0; j < NPW; ++j)
        hbuf_u[(size_t)(nbase + j) * 64 + lane] = pk2(sx[j], sy[j]);
}

// Persistent MFMA MLP: 512 blocks, weights staged ONCE per block, loop over tiles.
// reads h (bf16), writes h2 (bf16) IN PLACE; column sums in regs -> shadow at end.
__global__ __launch_bounds__(256, 2) void k_mlp(unsigned short* __restrict__ hbuf,
                                                const unsigned short* __restrict__ W1T,
                                                const unsigned short* __restrict__ W2T,
                                                const float* __restrict__ b1,
                                                const float* __restrict__ b2,
                                                float* __restrict__ shadow) {
    __shared__ short lds_x[BM * HID];        // 16KB: X / X2 per tile, colsums at end
    __shared__ short lds_w1[HID * HID];      // 32KB
    __shared__ short lds_w2[HID * HID];      // 32KB

    const int tid = threadIdx.x;

    // stage weights once (bf16 W^T [n][k]) with XOR swizzle on 16B chunks
    for (int c = tid; c < 2048; c += 256) {
        int n = c >> 4, k16 = c & 15;
        int4 v1 = ((const int4*)W1T)[c];
        int4 v2 = ((const int4*)W2T)[c];
        int boff = n * 256 + ((k16 * 16) ^ ((n & 7) << 4));
        *(int4*)((char*)lds_w1 + boff) = v1;
        *(int4*)((char*)lds_w2 + boff) = v2;
    }

    const int wid = tid >> 6, lane = tid & 63;
    const int wrow = wid >> 1, wcol = wid & 1;
    const int l15 = lane & 15, l4 = lane >> 4;

    float b1g[4], b2g[4];
#pragma unroll
    for (int nf = 0; nf < 4; ++nf) {
        int n = wcol * 64 + nf * 16 + l15;
        b1g[nf] = b1[n];
        b2g[nf] = b2[n];
    }

    float psum[4] = {0.f, 0.f, 0.f, 0.f}, psq[4] = {0.f, 0.f, 0.f, 0.f};

    __syncthreads();   // weights ready

    for (int tile = blockIdx.x; tile < NTILES; tile += MLP_BLOCKS) {
        const int m0 = tile * BM;

        // stage X rows (already bf16): int4 copy into swizzled layout
        for (int c = tid; c < BM * 16; c += 256) {
            int r = c >> 4, k16 = c & 15;
            int row = m0 + r;
            int4 v = {0, 0, 0, 0};
            if (row < N_NODES)
                v = ((const int4*)(hbuf + (size_t)row * HID))[k16];
            int boff = r * 256 + ((k16 * 16) ^ ((r & 7) << 4));
            *(int4*)((char*)lds_x + boff) = v;
        }
        __syncthreads();

        // GEMM1: Y = X @ W1
        f32x4 acc1[2][4];
#pragma unroll
        for (int mf = 0; mf < 2; ++mf)
#pragma unroll
            for (int nf = 0; nf < 4; ++nf) acc1[mf][nf] = (f32x4){0.f, 0.f, 0.f, 0.f};

#pragma unroll
        for (int kc = 0; kc < 4; ++kc) {
            bf16x8 av[2], bv[4];
#pragma unroll
            for (int mf = 0; mf < 2; ++mf) {
                int r = wrow * 32 + mf * 16 + l15;
                int boff = r * 256 + (((kc * 64) + l4 * 16) ^ ((r & 7) << 4));
                av[mf] = *(const bf16x8*)((const char*)lds_x + boff);
            }
#pragma unroll
            for (int nf = 0; nf < 4; ++nf) {
                int n = wcol * 64 + nf * 16 + l15;
                int boff = n * 256 + (((kc * 64) + l4 * 16) ^ ((n & 7) << 4));
                bv[nf] = *(const bf16x8*)((const char*)lds_w1 + boff);
            }
#pragma unroll
            for (int mf = 0; mf < 2; ++mf)
#pragma unroll
                for (int nf = 0; nf < 4; ++nf)
                    acc1[mf][nf] = __builtin_amdgcn_mfma_f32_16x16x32_bf16(av[mf], bv[nf], acc1[mf][nf], 0, 0, 0);
        }

        __syncthreads();

        // bias1 + ReLU -> X2 (bf16, swizzled) into lds_x
#pragma unroll
        for (int mf = 0; mf < 2; ++mf)
#pragma unroll
            for (int nf = 0; nf < 4; ++nf) {
                int n = wcol * 64 + nf * 16 + l15;
#pragma unroll
                for (int r = 0; r < 4; ++r) {
                    int row = wrow * 32 + mf * 16 + l4 * 4 + r;
                    float v = fmaxf(acc1[mf][nf][r] + b1g[nf], 0.f);
                    int boff = row * 256 + ((2 * n) ^ ((row & 7) << 4));
                    *(unsigned short*)((char*)lds_x + boff) = f2bf(v);
                }
            }

        __syncthreads();

        // GEMM2: h2 = X2 @ W2
        f32x4 acc2[2][4];
#pragma unroll
        for (int mf = 0; mf < 2; ++mf)
#pragma unroll
            for (int nf = 0; nf < 4; ++nf) acc2[mf][nf] = (f32x4){0.f, 0.f, 0.f, 0.f};

#pragma unroll
        for (int kc = 0; kc < 4; ++kc) {
            bf16x8 av[2], bv[4];
#pragma unroll
            for (int mf = 0; mf < 2; ++mf) {
                int r = wrow * 32 + mf * 16 + l15;
                int boff = r * 256 + (((kc * 64) + l4 * 16) ^ ((r & 7) << 4));
                av[mf] = *(const bf16x8*)((const char*)lds_x + boff);
            }
#pragma unroll
            for (int nf = 0; nf < 4; ++nf) {
                int n = wcol * 64 + nf * 16 + l15;
                int boff = n * 256 + (((kc * 64) + l4 * 16) ^ ((n & 7) << 4));
                bv[nf] = *(const bf16x8*)((const char*)lds_w2 + boff);
            }
#pragma unroll
            for (int mf = 0; mf < 2; ++mf)
#pragma unroll
                for (int nf = 0; nf < 4; ++nf)
                    acc2[mf][nf] = __builtin_amdgcn_mfma_f32_16x16x32_bf16(av[mf], bv[nf], acc2[mf][nf], 0, 0, 0);
        }

        // epilogue: bias2, quantize h2 -> bf16 in place, column partials in regs
#pragma unroll
        for (int mf = 0; mf < 2; ++mf)
#pragma unroll
            for (int nf = 0; nf < 4; ++nf) {
                int n = wcol * 64 + nf * 16 + l15;
#pragma unroll
                for (int r = 0; r < 4; ++r) {
                    int row = m0 + wrow * 32 + mf * 16 + l4 * 4 + r;
                    float v = acc2[mf][nf][r] + b2g[nf];
                    if (row < N_NODES) {
                        unsigned short q = f2bf(v);
                        float vq = __uint_as_float(((unsigned)q) << 16);
                        hbuf[(size_t)row * HID + n] = q;
                        psum[nf] += vq;
                        psq[nf] += vq * vq;
                    }
                }
            }

        __syncthreads();   // all GEMM2 LDS reads done before next tile's X staging
    }

    // final column-sum reduction: wave shuffle -> LDS -> one shadow add
    float* cs = (float*)lds_x;
    cs[tid] = 0.f;
    __syncthreads();
#pragma unroll
    for (int nf = 0; nf < 4; ++nf) {
        float s = psum[nf], q = psq[nf];
        s += __shfl_xor(s, 16); q += __shfl_xor(q, 16);
        s += __shfl_xor(s, 32); q += __shfl_xor(q, 32);
        if (lane < 16) {
            int n = wcol * 64 + nf * 16 + lane;
            atomicAdd(&cs[n], s);
            atomicAdd(&cs[HID + n], q);
        }
    }
    __syncthreads();
    atomicAdd(&shadow[(blockIdx.x & 63) * 256 + tid], cs[tid]);
}

// Fused finalize + BN apply: each block derives scale/shift from shadow (LDS),
// then grid-strides the bf16 h2 -> fp32 out stream.
__global__ __launch_bounds__(256) void k_bn2(const unsigned short* __restrict__ h2,
                                             const float* __restrict__ shadow,
                                             const float* __restrict__ gamma,
                                             const float* __restrict__ beta,
                                             float* __restrict__ out) {
    __shared__ float sc[256];                // scale[128], shift[128]
    int tid = threadIdx.x;
    if (tid < 128) {
        float sum = 0.f, sq = 0.f;
        for (int i = 0; i < 64; ++i) {
            sum += shadow[i * 256 + tid];
            sq  += shadow[i * 256 + 128 + tid];
        }
        float mean = sum * (1.0f / N_NODES);
        float var  = sq * (1.0f / N_NODES) - mean * mean;
        float r = rsqrtf(var + BN_EPS);
        float scale = gamma[tid] * r;
        sc[tid]       = scale;
        sc[128 + tid] = beta[tid] - mean * scale;
    }
    __syncthreads();
    int c4 = tid & 31;
    float4 scale = ((const float4*)sc)[c4];
    float4 shift = ((const float4*)sc)[32 + c4];
    const int total = N_NODES * HID / 4;               // 3,200,000 uint2 groups
    for (int t = blockIdx.x * 256 + tid; t < total; t += BN_BLOCKS * 256) {
        uint2 hv = ((const uint2*)h2)[t];
        float4 o;
        o.x = bflo(hv.x) * scale.x + shift.x;
        o.y = bfhi(hv.x) * scale.y + shift.y;
        o.z = bflo(hv.y) * scale.z + shift.z;
        o.w = bfhi(hv.y) * scale.w + shift.w;
        ((float4*)out)[t] = o;
    }
}

extern "C" void kernel_launch(void* const* d_in, const int* in_sizes, int n_in,
                              void* d_out, int out_size, void* d_ws, size_t ws_size,
                              hipStream_t stream) {
    const float* x0 = (const float*)d_in[0];
    const float* x1 = (const float*)d_in[1];
    const int*   ei = (const int*)d_in[2];
    const float* mw = (const float*)d_in[3];
    const float* W1 = (const float*)d_in[4];
    const float* b1 = (const float*)d_in[5];
    const float* W2 = (const float*)d_in[6];
    const float* b2 = (const float*)d_in[7];
    const float* gamma = (const float*)d_in[8];
    const float* beta  = (const float*)d_in[9];

    float* out = (float*)d_out;                            // gate(bf16) scratch -> final fp32

    unsigned short* hbuf = (unsigned short*)d_ws;          // 12.8M bf16 (h, then h2)
    float* shadow = (float*)(hbuf + (size_t)N_NODES * HID);// 16384
    float* sc     = shadow + 16384;                        // 256 (unused, layout keep)
    unsigned short* W1T = (unsigned short*)(sc + 256);     // 16384 u16
    unsigned short* W2T = W1T + 16384;                     // 16384 u16
    int* head    = (int*)(W2T + 16384);                    // 16 * 100,000
    int2* pair   = (int2*)(head + NSUB * N_NODES);         // 1,600,000 int2 (8B aligned)

    // head = -1 (0xFF bytes); async memset is graph-capture safe
    hipMemsetAsync(head, 0xFF, (size_t)NSUB * N_NODES * sizeof(int), stream);

    // fused gate + build: 12500 gate blocks + 6250 build blocks, interleaved 2:1
    k_front<<<18750, 256, 0, stream>>>(x0, x1, mw, (unsigned*)out, shadow,
                                       W1, W2, W1T, W2T, ei, head, pair);
    k_agg<<<N_NODES / (4 * NPW), 256, 0, stream>>>((const unsigned*)out, pair, head,
                                                   (unsigned*)hbuf);
    k_mlp<<<MLP_BLOCKS, 256, 0, stream>>>(hbuf, W1T, W2T, b1, b2, shadow);
    k_bn2<<<BN_BLOCKS, 256, 0, stream>>>(hbuf, shadow, gamma, beta, out);
}

// Round 12
// 237.801 us; speedup vs baseline: 1.4641x; 1.0181x over previous
//
#include <hip/hip_runtime.h>
#include <math.h>

#define N_NODES 100000
#define N_EDGES 1600000
#define HID 128
#define BN_EPS 1e-5f
#define BM 64
#define NTILES ((N_NODES + BM - 1) / BM)   // 1563
#define MLP_BLOCKS 512
#define NSUB 16   // sublists per node -> avg chain length 1
#define NPW 4     // nodes per wave (NPW*NSUB = 64 chains, one per lane)
#define BN_BLOCKS 512

typedef __attribute__((ext_vector_type(8))) short bf16x8;
typedef __attribute__((ext_vector_type(4))) float f32x4;

__device__ inline unsigned short f2bf(float f) {
    unsigned u = __float_as_uint(f);
    unsigned r = u + 0x7FFFu + ((u >> 16) & 1u);   // RNE
    return (unsigned short)(r >> 16);
}
__device__ inline unsigned pk2(float lo, float hi) {
    return (unsigned)f2bf(lo) | ((unsigned)f2bf(hi) << 16);
}
__device__ inline float bflo(unsigned u) { return __uint_as_float(u << 16); }
__device__ inline float bfhi(unsigned u) { return __uint_as_float(u & 0xffff0000u); }

// Fused front: 2/3 of blocks do gate (bf16 cast + shadow zero + W prep),
// 1/3 do linked-list build. Independent work; head pre-initialized by memset.
__global__ __launch_bounds__(256) void k_front(const float* __restrict__ x0,
                                               const float* __restrict__ x1,
                                               const float* __restrict__ mw,
                                               unsigned* __restrict__ gate_u2,
                                               float* __restrict__ shadow,
                                               const float* __restrict__ W1,
                                               const float* __restrict__ W2,
                                               unsigned short* __restrict__ W1T,
                                               unsigned short* __restrict__ W2T,
                                               const int* __restrict__ ei,
                                               int* __restrict__ head,
                                               int2* __restrict__ pair) {
    int bid = blockIdx.x, tid = threadIdx.x;
    int role = bid % 3;
    if (role < 2) {
        // gate block: gid in [0, 12500)
        int gid = (bid / 3) * 2 + role;
        int t = gid * 256 + tid;                       // 4-elem group index
        if (gid < 64) {
            shadow[t] = 0.0f;
            int k = t >> 7, n = t & 127;               // t < 16384
            W1T[n * HID + k] = f2bf(W1[t]);
            W2T[n * HID + k] = f2bf(W2[t]);
        }
        float s0 = 1.0f / (1.0f + expf(-mw[0]));
        float s1 = 1.0f / (1.0f + expf(-mw[1]));
        float4 a = ((const float4*)x0)[t];
        float4 b = ((const float4*)x1)[t];
        uint2 o;
        o.x = pk2(s0 * a.x + s1 * b.x, s0 * a.y + s1 * b.y);
        o.y = pk2(s0 * a.z + s1 * b.z, s0 * a.w + s1 * b.w);
        ((uint2*)gate_u2)[t] = o;
    } else {
        // build block: gid in [0, 6250)
        int e = (bid / 3) * 256 + tid;                 // exact: N_EDGES threads
        int src = ei[e];
        int dst = ei[N_EDGES + e];
        int old = atomicExch(&head[dst * NSUB + (e & (NSUB - 1))], e);
        pair[e] = make_int2(src, old);
    }
}

// gather-sum: 64 chains per wave (one per lane), wave-wide dense row gathers.
// head is node-major: per-wave chain-head read is one contiguous 256B block.
__global__ __launch_bounds__(256) void k_agg(const unsigned* __restrict__ gu,
                                             const int2* __restrict__ pair,
                                             const int* __restrict__ head,
                                             unsigned* __restrict__ hbuf_u) {
    int wid = threadIdx.x >> 6, lane = threadIdx.x & 63;
    int nbase = (blockIdx.x * 4 + wid) * NPW;          // exact: 6250 blocks
    // lane l owns chain (node nbase + (l>>4), sublist l&15)
    int e = head[(nbase + (lane >> 4)) * NSUB + (lane & 15)];

    float sx[NPW], sy[NPW];
#pragma unroll
    for (int j = 0; j < NPW; ++j) {
        unsigned g = gu[(size_t)(nbase + j) * 64 + lane];   // self row
        sx[j] = bflo(g); sy[j] = bfhi(g);
    }

    while (__any(e >= 0)) {
        int2 pv = make_int2(-1, -1);
        if (e >= 0) pv = pair[e];                      // one dense per-lane clause
#pragma unroll
        for (int j = 0; j < 64; ++j) {
            int sv = __builtin_amdgcn_readlane(pv.x, j);   // SGPR; scalar skip
            if (sv >= 0) {
                unsigned v = gu[(size_t)sv * 64 + lane];   // wave-wide 256B gather
                sx[j >> 4] += bflo(v);
                sy[j >> 4] += bfhi(v);
            }
        }
        e = pv.y;
    }
#pragma unroll
    for (int j = 0; j < NPW; ++j)
        hbuf_u[(size_t)(nbase + j) * 64 + lane] = pk2(sx[j], sy[j]);
}

// Persistent MFMA MLP: 512 blocks, weights staged ONCE, register-prefetched X.
// reads h (bf16), writes h2 (bf16) IN PLACE; column sums in regs -> shadow at end.
__global__ __launch_bounds__(256, 2) void k_mlp(unsigned short* __restrict__ hbuf,
                                                const unsigned short* __restrict__ W1T,
                                                const unsigned short* __restrict__ W2T,
                                                const float* __restrict__ b1,
                                                const float* __restrict__ b2,
                                                float* __restrict__ shadow) {
    __shared__ short lds_x[BM * HID];        // 16KB: X / X2 per tile, colsums at end
    __shared__ short lds_w1[HID * HID];      // 32KB
    __shared__ short lds_w2[HID * HID];      // 32KB

    const int tid = threadIdx.x;

    // stage weights once (bf16 W^T [n][k]) with XOR swizzle on 16B chunks
    for (int c = tid; c < 2048; c += 256) {
        int n = c >> 4, k16 = c & 15;
        int4 v1 = ((const int4*)W1T)[c];
        int4 v2 = ((const int4*)W2T)[c];
        int boff = n * 256 + ((k16 * 16) ^ ((n & 7) << 4));
        *(int4*)((char*)lds_w1 + boff) = v1;
        *(int4*)((char*)lds_w2 + boff) = v2;
    }

    const int wid = tid >> 6, lane = tid & 63;
    const int wrow = wid >> 1, wcol = wid & 1;
    const int l15 = lane & 15, l4 = lane >> 4;

    float b1g[4], b2g[4];
#pragma unroll
    for (int nf = 0; nf < 4; ++nf) {
        int n = wcol * 64 + nf * 16 + l15;
        b1g[nf] = b1[n];
        b2g[nf] = b2[n];
    }

    float psum[4] = {0.f, 0.f, 0.f, 0.f}, psq[4] = {0.f, 0.f, 0.f, 0.f};

    // prefetch first tile's X into registers (4 x int4 per thread)
    int4 xr[4];
    int tile0 = blockIdx.x;
#pragma unroll
    for (int i = 0; i < 4; ++i) {
        int c = tid + i * 256;                         // c in [0, 1024)
        int row = tile0 * BM + (c >> 4);
        xr[i] = make_int4(0, 0, 0, 0);
        if (tile0 < NTILES && row < N_NODES)
            xr[i] = ((const int4*)(hbuf + (size_t)row * HID))[c & 15];
    }

    __syncthreads();   // weights ready

    for (int tile = blockIdx.x; tile < NTILES; tile += MLP_BLOCKS) {
        const int m0 = tile * BM;

        // write prefetched X regs -> swizzled LDS
#pragma unroll
        for (int i = 0; i < 4; ++i) {
            int c = tid + i * 256;
            int r = c >> 4, k16 = c & 15;
            int boff = r * 256 + ((k16 * 16) ^ ((r & 7) << 4));
            *(int4*)((char*)lds_x + boff) = xr[i];
        }
        __syncthreads();

        // GEMM1: Y = X @ W1
        f32x4 acc1[2][4];
#pragma unroll
        for (int mf = 0; mf < 2; ++mf)
#pragma unroll
            for (int nf = 0; nf < 4; ++nf) acc1[mf][nf] = (f32x4){0.f, 0.f, 0.f, 0.f};

#pragma unroll
        for (int kc = 0; kc < 4; ++kc) {
            bf16x8 av[2], bv[4];
#pragma unroll
            for (int mf = 0; mf < 2; ++mf) {
                int r = wrow * 32 + mf * 16 + l15;
                int boff = r * 256 + (((kc * 64) + l4 * 16) ^ ((r & 7) << 4));
                av[mf] = *(const bf16x8*)((const char*)lds_x + boff);
            }
#pragma unroll
            for (int nf = 0; nf < 4; ++nf) {
                int n = wcol * 64 + nf * 16 + l15;
                int boff = n * 256 + (((kc * 64) + l4 * 16) ^ ((n & 7) << 4));
                bv[nf] = *(const bf16x8*)((const char*)lds_w1 + boff);
            }
#pragma unroll
            for (int mf = 0; mf < 2; ++mf)
#pragma unroll
                for (int nf = 0; nf < 4; ++nf)
                    acc1[mf][nf] = __builtin_amdgcn_mfma_f32_16x16x32_bf16(av[mf], bv[nf], acc1[mf][nf], 0, 0, 0);
        }

        __syncthreads();

        // bias1 + ReLU -> X2 (bf16, swizzled) into lds_x
#pragma unroll
        for (int mf = 0; mf < 2; ++mf)
#pragma unroll
            for (int nf = 0; nf < 4; ++nf) {
                int n = wcol * 64 + nf * 16 + l15;
#pragma unroll
                for (int r = 0; r < 4; ++r) {
                    int row = wrow * 32 + mf * 16 + l4 * 4 + r;
                    float v = fmaxf(acc1[mf][nf][r] + b1g[nf], 0.f);
                    int boff = row * 256 + ((2 * n) ^ ((row & 7) << 4));
                    *(unsigned short*)((char*)lds_x + boff) = f2bf(v);
                }
            }

        __syncthreads();

        // issue NEXT tile's X prefetch (overlaps GEMM2 + epilogue)
        int tnext = tile + MLP_BLOCKS;
#pragma unroll
        for (int i = 0; i < 4; ++i) {
            int c = tid + i * 256;
            int row = tnext * BM + (c >> 4);
            int4 v = make_int4(0, 0, 0, 0);
            if (tnext < NTILES && row < N_NODES)
                v = ((const int4*)(hbuf + (size_t)row * HID))[c & 15];
            xr[i] = v;
        }

        // GEMM2: h2 = X2 @ W2
        f32x4 acc2[2][4];
#pragma unroll
        for (int mf = 0; mf < 2; ++mf)
#pragma unroll
            for (int nf = 0; nf < 4; ++nf) acc2[mf][nf] = (f32x4){0.f, 0.f, 0.f, 0.f};

#pragma unroll
        for (int kc = 0; kc < 4; ++kc) {
            bf16x8 av[2], bv[4];
#pragma unroll
            for (int mf = 0; mf < 2; ++mf) {
                int r = wrow * 32 + mf * 16 + l15;
                int boff = r * 256 + (((kc * 64) + l4 * 16) ^ ((r & 7) << 4));
                av[mf] = *(const bf16x8*)((const char*)lds_x + boff);
            }
#pragma unroll
            for (int nf = 0; nf < 4; ++nf) {
                int n = wcol * 64 + nf * 16 + l15;
                int boff = n * 256 + (((kc * 64) + l4 * 16) ^ ((n & 7) << 4));
                bv[nf] = *(const bf16x8*)((const char*)lds_w2 + boff);
            }
#pragma unroll
            for (int mf = 0; mf < 2; ++mf)
#pragma unroll
                for (int nf = 0; nf < 4; ++nf)
                    acc2[mf][nf] = __builtin_amdgcn_mfma_f32_16x16x32_bf16(av[mf], bv[nf], acc2[mf][nf], 0, 0, 0);
        }

        // epilogue: bias2, quantize h2 -> bf16 in place, column partials in regs
#pragma unroll
        for (int mf = 0; mf < 2; ++mf)
#pragma unroll
            for (int nf = 0; nf < 4; ++nf) {
                int n = wcol * 64 + nf * 16 + l15;
#pragma unroll
                for (int r = 0; r < 4; ++r) {
                    int row = m0 + wrow * 32 + mf * 16 + l4 * 4 + r;
                    float v = acc2[mf][nf][r] + b2g[nf];
                    if (row < N_NODES) {
                        unsigned short q = f2bf(v);
                        float vq = __uint_as_float(((unsigned)q) << 16);
                        hbuf[(size_t)row * HID + n] = q;
                        psum[nf] += vq;
                        psq[nf] += vq * vq;
                    }
                }
            }

        __syncthreads();   // all GEMM2 LDS reads done before next tile's X write
    }

    // final column-sum reduction: wave shuffle -> LDS -> one shadow add
    float* cs = (float*)lds_x;
    cs[tid] = 0.f;
    __syncthreads();
#pragma unroll
    for (int nf = 0; nf < 4; ++nf) {
        float s = psum[nf], q = psq[nf];
        s += __shfl_xor(s, 16); q += __shfl_xor(q, 16);
        s += __shfl_xor(s, 32); q += __shfl_xor(q, 32);
        if (lane < 16) {
            int n = wcol * 64 + nf * 16 + lane;
            atomicAdd(&cs[n], s);
            atomicAdd(&cs[HID + n], q);
        }
    }
    __syncthreads();
    atomicAdd(&shadow[(blockIdx.x & 63) * 256 + tid], cs[tid]);
}

// Fused finalize + BN apply: each block derives scale/shift from shadow (LDS),
// then grid-strides the bf16 h2 -> fp32 out stream.
__global__ __launch_bounds__(256) void k_bn2(const unsigned short* __restrict__ h2,
                                             const float* __restrict__ shadow,
                                             const float* __restrict__ gamma,
                                             const float* __restrict__ beta,
                                             float* __restrict__ out) {
    __shared__ float sc[256];                // scale[128], shift[128]
    int tid = threadIdx.x;
    if (tid < 128) {
        float sum = 0.f, sq = 0.f;
        for (int i = 0; i < 64; ++i) {
            sum += shadow[i * 256 + tid];
            sq  += shadow[i * 256 + 128 + tid];
        }
        float mean = sum * (1.0f / N_NODES);
        float var  = sq * (1.0f / N_NODES) - mean * mean;
        float r = rsqrtf(var + BN_EPS);
        float scale = gamma[tid] * r;
        sc[tid]       = scale;
        sc[128 + tid] = beta[tid] - mean * scale;
    }
    __syncthreads();
    int c4 = tid & 31;
    float4 scale = ((const float4*)sc)[c4];
    float4 shift = ((const float4*)sc)[32 + c4];
    const int total = N_NODES * HID / 4;               // 3,200,000 uint2 groups
    for (int t = blockIdx.x * 256 + tid; t < total; t += BN_BLOCKS * 256) {
        uint2 hv = ((const uint2*)h2)[t];
        float4 o;
        o.x = bflo(hv.x) * scale.x + shift.x;
        o.y = bfhi(hv.x) * scale.y + shift.y;
        o.z = bflo(hv.y) * scale.z + shift.z;
        o.w = bfhi(hv.y) * scale.w + shift.w;
        ((float4*)out)[t] = o;
    }
}

extern "C" void kernel_launch(void* const* d_in, const int* in_sizes, int n_in,
                              void* d_out, int out_size, void* d_ws, size_t ws_size,
                              hipStream_t stream) {
    const float* x0 = (const float*)d_in[0];
    const float* x1 = (const float*)d_in[1];
    const int*   ei = (const int*)d_in[2];
    const float* mw = (const float*)d_in[3];
    const float* W1 = (const float*)d_in[4];
    const float* b1 = (const float*)d_in[5];
    const float* W2 = (const float*)d_in[6];
    const float* b2 = (const float*)d_in[7];
    const float* gamma = (const float*)d_in[8];
    const float* beta  = (const float*)d_in[9];

    float* out = (float*)d_out;                            // gate(bf16) scratch -> final fp32

    unsigned short* hbuf = (unsigned short*)d_ws;          // 12.8M bf16 (h, then h2)
    float* shadow = (float*)(hbuf + (size_t)N_NODES * HID);// 16384
    float* sc     = shadow + 16384;                        // 256 (layout keep)
    unsigned short* W1T = (unsigned short*)(sc + 256);     // 16384 u16
    unsigned short* W2T = W1T + 16384;                     // 16384 u16
    int* head    = (int*)(W2T + 16384);                    // 100,000 * 16, node-major
    int2* pair   = (int2*)(head + NSUB * N_NODES);         // 1,600,000 int2 (8B aligned)

    // head = -1 (0xFF bytes); async memset is graph-capture safe
    hipMemsetAsync(head, 0xFF, (size_t)NSUB * N_NODES * sizeof(int), stream);

    // fused gate + build: 12500 gate blocks + 6250 build blocks, interleaved 2:1
    k_front<<<18750, 256, 0, stream>>>(x0, x1, mw, (unsigned*)out, shadow,
                                       W1, W2, W1T, W2T, ei, head, pair);
    k_agg<<<N_NODES / (4 * NPW), 256, 0, stream>>>((const unsigned*)out, pair, head,
                                                   (unsigned*)hbuf);
    k_mlp<<<MLP_BLOCKS, 256, 0, stream>>>(hbuf, W1T, W2T, b1, b2, shadow);
    k_bn2<<<BN_BLOCKS, 256, 0, stream>>>(hbuf, shadow, gamma, beta, out);
}